// Round 1
// baseline (627.258 us; speedup 1.0000x reference)
//
#include <hip/hip_runtime.h>
#include <hip/hip_bf16.h>
#include <math.h>

// Sizes (fixed by the problem)
#define LL 65536      // H*W
#define HH 256
#define WW 256
#define BB 2
#define DIMC 128
#define QKVC 384
#define NH 8
#define CH 16

typedef __hip_bfloat16 bf16;

static __device__ __forceinline__ float b2f(bf16 v){ return __bfloat162float(v); }
static __device__ __forceinline__ bf16  f2b(float v){ return __float2bfloat16(v); }

// ---------------------------------------------------------------------------
// K0: transpose qkv weights [384,128] -> wt[i][o] (128x384) so the 1x1-conv
// kernel can read 16 consecutive output-channel weights with one (scalar) load.
__global__ void k_wt(const float* __restrict__ w, float* __restrict__ wt){
  int idx = blockIdx.x*256 + threadIdx.x;
  if (idx < QKVC*DIMC){ int o = idx / DIMC, i = idx % DIMC; wt[i*QKVC + o] = w[idx]; }
}

// ---------------------------------------------------------------------------
// K1: pointwise qkv conv.  thread = one pixel l; loops output channels in
// chunks of 48 (acc in VGPRs), weights are wave-uniform -> s_load.
__global__ __launch_bounds__(256) void k_pw(const float* __restrict__ x,
                                            const float* __restrict__ wt,
                                            bf16* __restrict__ qkv){
  int bid = blockIdx.x;
  int b = bid >> 8;                       // 256 l-blocks per batch
  int l = ((bid & 255) << 8) + threadIdx.x;
  const float* xb = x + (size_t)b*DIMC*LL + l;
  bf16* qb = qkv + (size_t)b*QKVC*LL + l;
  for (int oc = 0; oc < 8; ++oc){         // 8 x 48 = 384 outputs
    float acc[48];
    #pragma unroll
    for (int j=0;j<48;++j) acc[j]=0.f;
    const float* wtoc = wt + oc*48;
    #pragma unroll 2
    for (int i=0;i<DIMC;++i){
      float xv = xb[(size_t)i*LL];
      const float4* w4 = (const float4*)(wtoc + i*QKVC);
      #pragma unroll
      for (int j4=0;j4<12;++j4){
        float4 wv = w4[j4];
        acc[j4*4+0] = fmaf(xv, wv.x, acc[j4*4+0]);
        acc[j4*4+1] = fmaf(xv, wv.y, acc[j4*4+1]);
        acc[j4*4+2] = fmaf(xv, wv.z, acc[j4*4+2]);
        acc[j4*4+3] = fmaf(xv, wv.w, acc[j4*4+3]);
      }
    }
    #pragma unroll
    for (int j=0;j<48;++j) qb[(size_t)(oc*48+j)*LL] = f2b(acc[j]);
  }
}

// ---------------------------------------------------------------------------
// K2: 3x3 depthwise conv (SAME, zero pad), one (b, channel, 8-row block) per
// block; 256 threads = one per column.  Rows staged in LDS as f32.
__global__ __launch_bounds__(256) void k_dw(const bf16* __restrict__ qkv,
                                            const float* __restrict__ dw,
                                            bf16* __restrict__ out){
  int bid = blockIdx.x;
  int rb = bid & 31;
  int ch = (bid >> 5) % QKVC;
  int b  = bid / (QKVC*32);
  int col = threadIdx.x;
  __shared__ float s[10][WW];
  const bf16* src = qkv + (size_t)(b*QKVC + ch)*LL;
  float wk[9];
  #pragma unroll
  for (int t=0;t<9;++t) wk[t] = dw[ch*9 + t];
  int r0 = rb*8;
  #pragma unroll
  for (int rr=0; rr<10; ++rr){
    int row = r0 - 1 + rr;
    s[rr][col] = (row >= 0 && row < HH) ? b2f(src[row*WW + col]) : 0.f;
  }
  __syncthreads();
  bf16* dst = out + (size_t)(b*QKVC + ch)*LL;
  #pragma unroll
  for (int r=0;r<8;++r){
    float acc = 0.f;
    #pragma unroll
    for (int dy=0;dy<3;++dy){
      float left  = (col>0)      ? s[r+dy][col-1] : 0.f;
      float mid   =                s[r+dy][col];
      float right = (col<WW-1)   ? s[r+dy][col+1] : 0.f;
      acc = fmaf(left,  wk[dy*3+0], acc);
      acc = fmaf(mid,   wk[dy*3+1], acc);
      acc = fmaf(right, wk[dy*3+2], acc);
    }
    dst[(r0+r)*WW + col] = f2b(acc);
  }
}

// ---------------------------------------------------------------------------
// K3: Gram matrices S[b,h,c,d] = sum_l q[c,l]k[d,l] plus ||q_c||^2, ||k_d||^2.
// thread (c,d) accumulates over a 2048-pixel chunk; atomicAdd partials.
__global__ __launch_bounds__(256) void k_gram(const bf16* __restrict__ qkvd,
                                              float* __restrict__ S,
                                              float* __restrict__ nq,
                                              float* __restrict__ nk){
  int bid = blockIdx.x;
  int lc = bid & 31;
  int h  = (bid >> 5) & 7;
  int b  = bid >> 8;
  int tid = threadIdx.x;
  int c = tid >> 4, d = tid & 15;
  __shared__ float qs[16][260];   // pad 260: c-groups land on distinct banks
  __shared__ float ks[16][260];
  const bf16* qbase = qkvd + (size_t)(b*QKVC +        h*CH)*LL;
  const bf16* kbase = qkvd + (size_t)(b*QKVC + DIMC + h*CH)*LL;
  float acc = 0.f, accq = 0.f, acck = 0.f;
  for (int it=0; it<8; ++it){
    int l0 = lc*2048 + it*256;
    #pragma unroll
    for (int r=0;r<16;++r){
      qs[r][tid] = b2f(qbase[(size_t)r*LL + l0 + tid]);
      ks[r][tid] = b2f(kbase[(size_t)r*LL + l0 + tid]);
    }
    __syncthreads();
    #pragma unroll 4
    for (int j=0;j<256;++j){
      float qv = qs[c][j], kv = ks[d][j];
      acc = fmaf(qv, kv, acc);
      if (d==0) accq = fmaf(qv, qv, accq);
      if (c==0) acck = fmaf(kv, kv, acck);
    }
    __syncthreads();
  }
  atomicAdd(&S[((b*NH + h)*CH + c)*CH + d], acc);
  if (d==0) atomicAdd(&nq[(b*NH + h)*CH + c], accq);
  if (c==0) atomicAdd(&nk[(b*NH + h)*CH + d], acck);
}

// ---------------------------------------------------------------------------
// K4: finalize attention (normalize, softmax, relu^2/gelu gate, scale/shift)
// and fold proj into a per-batch 128x128 matrix  Mt[j][o] = sum_c proj[o,hc]*attnf[h,c,d]
__global__ __launch_bounds__(256) void k_fin(const float* __restrict__ S,
                                             const float* __restrict__ nq,
                                             const float* __restrict__ nk,
                                             const float* __restrict__ temp,
                                             const float* __restrict__ attca,
                                             const float* __restrict__ proj,
                                             float* __restrict__ Mt){
  int b = blockIdx.x;
  int t = threadIdx.x;
  __shared__ float attnf[NH][CH][CH];
  __shared__ float pl[DIMC*DIMC];   // proj staged: 64 KB
  for (int idx=t; idx<DIMC*DIMC; idx+=256) pl[idx] = proj[idx];
  if (t < 128){
    int h = t >> 4, c = t & 15;
    float tmpv = temp[h];
    float qn = fmaxf(sqrtf(nq[(b*NH+h)*CH + c]), 1e-12f);
    float row[CH], ex[CH], a1[CH];
    float m = -1e30f;
    #pragma unroll
    for (int d=0; d<CH; ++d){
      float kn = fmaxf(sqrtf(nk[(b*NH+h)*CH + d]), 1e-12f);
      float v = S[((b*NH+h)*CH + c)*CH + d] / (qn*kn) * tmpv;
      row[d] = v;
      m = fmaxf(m, v);
    }
    float sum = 0.f;
    #pragma unroll
    for (int d=0;d<CH;++d){ ex[d] = expf(row[d]-m); sum += ex[d]; }
    float inv = 1.f/sum;
    #pragma unroll
    for (int d=0;d<CH;++d){
      float r = fmaxf(row[d], 0.f);
      float xx = r*r;                                  // relu(attn)^2
      float g = 0.5f * xx * (1.f + erff(xx * 0.70710678118654752440f)); // exact gelu
      a1[d] = g * xx;                                  // gelu(a1)*a1
    }
    #pragma unroll
    for (int j=0;j<CH;++j){
      float sc=0.f, sh=0.f;
      #pragma unroll
      for (int i=0;i<CH;++i){
        sc = fmaf(attca[j*CH+i],      a1[i], sc);
        sh = fmaf(attca[(CH+j)*CH+i], a1[i], sh);
      }
      attnf[h][c][j] = ex[j]*inv*(1.f+sc) + sh;
    }
  }
  __syncthreads();
  for (int idx=t; idx<DIMC*DIMC; idx+=256){
    int j = idx >> 7, o = idx & 127;
    int h = j >> 4, d = j & 15;
    float s = 0.f;
    #pragma unroll
    for (int c2=0;c2<CH;++c2) s = fmaf(pl[o*DIMC + h*CH + c2], attnf[h][c2][d], s);
    Mt[((size_t)b*DIMC + j)*DIMC + o] = s;
  }
}

// ---------------------------------------------------------------------------
// K5: out[b,o,l] = sum_j Mt[b,j,o] * v[b,j,l]   (PV and proj fused via Mt)
__global__ __launch_bounds__(256) void k_out(const bf16* __restrict__ qkvd,
                                             const float* __restrict__ Mt,
                                             float* __restrict__ out){
  int bid = blockIdx.x;
  int b = bid >> 8;
  int l = ((bid & 255) << 8) + threadIdx.x;
  const bf16* vb = qkvd + (size_t)(b*QKVC + 2*DIMC)*LL + l;
  float* ob = out + (size_t)b*DIMC*LL + l;
  const float* Mb = Mt + (size_t)b*DIMC*DIMC;
  for (int oc=0; oc<4; ++oc){             // 4 x 32 = 128 outputs
    float acc[32];
    #pragma unroll
    for (int j=0;j<32;++j) acc[j]=0.f;
    #pragma unroll 2
    for (int j=0;j<DIMC;++j){
      float vv = b2f(vb[(size_t)j*LL]);
      const float4* m4 = (const float4*)(Mb + j*DIMC + oc*32);
      #pragma unroll
      for (int q4=0;q4<8;++q4){
        float4 mv = m4[q4];
        acc[q4*4+0] = fmaf(vv, mv.x, acc[q4*4+0]);
        acc[q4*4+1] = fmaf(vv, mv.y, acc[q4*4+1]);
        acc[q4*4+2] = fmaf(vv, mv.z, acc[q4*4+2]);
        acc[q4*4+3] = fmaf(vv, mv.w, acc[q4*4+3]);
      }
    }
    #pragma unroll
    for (int j=0;j<32;++j) ob[(size_t)(oc*32+j)*LL] = acc[j];
  }
}

// ---------------------------------------------------------------------------
extern "C" void kernel_launch(void* const* d_in, const int* in_sizes, int n_in,
                              void* d_out, int out_size, void* d_ws, size_t ws_size,
                              hipStream_t stream){
  const float* x      = (const float*)d_in[0];
  const float* qkv_w  = (const float*)d_in[1];
  const float* dw_w   = (const float*)d_in[2];
  const float* proj_w = (const float*)d_in[3];
  const float* attca  = (const float*)d_in[4];
  const float* temp   = (const float*)d_in[5];
  float* out = (float*)d_out;

  char* ws = (char*)d_ws;
  size_t off = 0;
  bf16* qkv_pw = (bf16*)(ws + off); off += (size_t)BB*QKVC*LL*2;   // 100.7 MB
  bf16* qkv_dw = (bf16*)(ws + off); off += (size_t)BB*QKVC*LL*2;   // 100.7 MB
  float* wt    = (float*)(ws + off); off += (size_t)QKVC*DIMC*4;
  float* S     = (float*)(ws + off); off += (size_t)BB*NH*CH*CH*4; // S, nq, nk contiguous
  float* nq    = (float*)(ws + off); off += (size_t)BB*NH*CH*4;
  float* nk    = (float*)(ws + off); off += (size_t)BB*NH*CH*4;
  float* Mt    = (float*)(ws + off); off += (size_t)BB*DIMC*DIMC*4;
  // total ~201.7 MB of ws

  // zero the atomic accumulators (ws is poisoned before every launch)
  hipMemsetAsync(S, 0, (size_t)(BB*NH*CH*CH + 2*BB*NH*CH)*4, stream);

  k_wt  <<<(QKVC*DIMC + 255)/256, 256, 0, stream>>>(qkv_w, wt);
  k_pw  <<<BB*256,      256, 0, stream>>>(x, wt, qkv_pw);
  k_dw  <<<BB*QKVC*32,  256, 0, stream>>>(qkv_pw, dw_w, qkv_dw);
  k_gram<<<BB*NH*32,    256, 0, stream>>>(qkv_dw, S, nq, nk);
  k_fin <<<BB,          256, 0, stream>>>(S, nq, nk, temp, attca, proj_w, Mt);
  k_out <<<BB*256,      256, 0, stream>>>(qkv_dw, Mt, out);
}

// Round 2
// 257.814 us; speedup vs baseline: 2.4330x; 2.4330x over previous
//
#include <hip/hip_runtime.h>
#include <hip/hip_bf16.h>
#include <math.h>

#define LL 65536      // H*W
#define HH 256
#define WW 256
#define BB 2
#define DIMC 128
#define QKVC 384
#define NH 8
#define CH 16

typedef __hip_bfloat16 bf16;
typedef __attribute__((ext_vector_type(8))) __bf16 bf16x8;
typedef __attribute__((ext_vector_type(4))) float f32x4;
typedef __attribute__((ext_vector_type(4))) unsigned int u32x4;

static __device__ __forceinline__ float b2f(bf16 v){ return __bfloat162float(v); }
static __device__ __forceinline__ bf16  f2b(float v){ return __float2bfloat16(v); }
static __device__ __forceinline__ unsigned short fbits(float v){
  return __builtin_bit_cast(unsigned short, __float2bfloat16(v));
}

// ---------------------------------------------------------------------------
// K0: convert qkv weights [384][128] f32 -> bf16 bits (A-fragment friendly:
// row o, contiguous c).
__global__ void k_wb(const float* __restrict__ w, unsigned short* __restrict__ wb){
  int idx = blockIdx.x*256 + threadIdx.x;
  if (idx < QKVC*DIMC) wb[idx] = fbits(w[idx]);
}

// ---------------------------------------------------------------------------
// K1: pointwise qkv conv via MFMA.  Block = one 128-pixel l-tile x all 384 o.
// X tile staged f32->bf16 in LDS as [l][c], XOR-swizzled granules (16B = 8 c).
// 8 waves x (48 o x 128 l); A-frags from global (Wb is L1/L2 resident).
__global__ __launch_bounds__(512) void k_pw(const float* __restrict__ x,
                                            const unsigned short* __restrict__ wb,
                                            unsigned short* __restrict__ qkv){
  __shared__ u32x4 lds4[2048];              // 32 KB: [l=128][c=128] bf16 swizzled
  char* lds = (char*)lds4;
  int bid = blockIdx.x;
  int b = bid >> 9;                         // 512 l-tiles per batch
  int l0 = (bid & 511) << 7;
  int tid = threadIdx.x;
  const float* xb = x + (size_t)b*DIMC*LL;

  // stage: task = (oct 0..15, l 0..127); thread reads 8 f32 (one c-octet) and
  // writes one swizzled b128 of 8 bf16.
  #pragma unroll
  for (int it=0; it<4; ++it){
    int task = it*512 + tid;
    int l   = task & 127;
    int oct = task >> 7;
    float v[8];
    #pragma unroll
    for (int e=0;e<8;++e) v[e] = xb[(size_t)(oct*8+e)*LL + l0 + l];
    u32x4 p;
    #pragma unroll
    for (int k=0;k<4;++k){
      unsigned lo = fbits(v[2*k]);
      unsigned hi = fbits(v[2*k+1]);
      p[k] = lo | (hi<<16);
    }
    *(u32x4*)(lds + l*256 + ((oct ^ (l&15))<<4)) = p;
  }
  __syncthreads();

  int wid = tid >> 6, lane = tid & 63;
  int r = lane & 15, kg = lane >> 4;        // r: row/col within frag, kg: k-group
  int ob = wid * 48;
  f32x4 acc[3][8];
  #pragma unroll
  for (int ft=0; ft<3; ++ft)
    #pragma unroll
    for (int nt=0; nt<8; ++nt) acc[ft][nt] = (f32x4)0.f;

  #pragma unroll
  for (int kb=0; kb<4; ++kb){
    bf16x8 a[3], bf[8];
    #pragma unroll
    for (int ft=0; ft<3; ++ft)
      a[ft] = *(const bf16x8*)(wb + (size_t)(ob + ft*16 + r)*DIMC + kb*32 + kg*8);
    #pragma unroll
    for (int nt=0; nt<8; ++nt){
      int l = nt*16 + r;
      bf[nt] = *(const bf16x8*)(lds + l*256 + (((kb*4 + kg) ^ r)<<4));
    }
    #pragma unroll
    for (int ft=0; ft<3; ++ft)
      #pragma unroll
      for (int nt=0; nt<8; ++nt)
        acc[ft][nt] = __builtin_amdgcn_mfma_f32_16x16x32_bf16(a[ft], bf[nt], acc[ft][nt], 0,0,0);
  }

  unsigned short* qb = qkv + (size_t)b*QKVC*LL + l0;
  #pragma unroll
  for (int ft=0; ft<3; ++ft)
    #pragma unroll
    for (int nt=0; nt<8; ++nt)
      #pragma unroll
      for (int i=0;i<4;++i){
        int o = ob + ft*16 + kg*4 + i;      // C/D: col=lane&15, row=(lane>>4)*4+i
        qb[(size_t)o*LL + nt*16 + r] = fbits(acc[ft][nt][i]);
      }
}

// ---------------------------------------------------------------------------
// K2: 3x3 depthwise conv (SAME), one (b, channel, 8-row block) per block.
__global__ __launch_bounds__(256) void k_dw(const bf16* __restrict__ qkv,
                                            const float* __restrict__ dw,
                                            bf16* __restrict__ out){
  int bid = blockIdx.x;
  int rb = bid & 31;
  int ch = (bid >> 5) % QKVC;
  int b  = bid / (QKVC*32);
  int col = threadIdx.x;
  __shared__ float s[10][WW];
  const bf16* src = qkv + (size_t)(b*QKVC + ch)*LL;
  float wk[9];
  #pragma unroll
  for (int t=0;t<9;++t) wk[t] = dw[ch*9 + t];
  int r0 = rb*8;
  #pragma unroll
  for (int rr=0; rr<10; ++rr){
    int row = r0 - 1 + rr;
    s[rr][col] = (row >= 0 && row < HH) ? b2f(src[row*WW + col]) : 0.f;
  }
  __syncthreads();
  bf16* dst = out + (size_t)(b*QKVC + ch)*LL;
  #pragma unroll
  for (int r=0;r<8;++r){
    float acc = 0.f;
    #pragma unroll
    for (int dy=0;dy<3;++dy){
      float left  = (col>0)      ? s[r+dy][col-1] : 0.f;
      float mid   =                s[r+dy][col];
      float right = (col<WW-1)   ? s[r+dy][col+1] : 0.f;
      acc = fmaf(left,  wk[dy*3+0], acc);
      acc = fmaf(mid,   wk[dy*3+1], acc);
      acc = fmaf(right, wk[dy*3+2], acc);
    }
    dst[(r0+r)*WW + col] = f2b(acc);
  }
}

// ---------------------------------------------------------------------------
// K3: Gram matrices via MFMA.  q,k live in [ch][l] layout which IS the A/B
// fragment layout (8 contiguous l per lane).  3 MFMAs per k-step:
// S=q.k^T, qq^T (diag -> ||q||^2), kk^T (diag -> ||k||^2).  atomicAdd reduce.
__global__ __launch_bounds__(256) void k_gram(const unsigned short* __restrict__ qkvd,
                                              float* __restrict__ S,
                                              float* __restrict__ nq,
                                              float* __restrict__ nk){
  int bid = blockIdx.x;
  int chunk = bid & 63;
  int h = (bid>>6)&7;
  int b = bid>>9;
  int tid = threadIdx.x, wid = tid>>6, lane = tid&63;
  int r = lane&15, kg = lane>>4;
  int l0 = chunk*1024 + wid*256;
  const unsigned short* qb = qkvd + (size_t)(b*QKVC + h*CH)*LL;
  const unsigned short* kb = qkvd + (size_t)(b*QKVC + DIMC + h*CH)*LL;
  f32x4 sqk = (f32x4)0.f, sqq = (f32x4)0.f, skk = (f32x4)0.f;
  #pragma unroll 4
  for (int ks=0; ks<8; ++ks){
    int l = l0 + ks*32 + kg*8;
    bf16x8 qf = *(const bf16x8*)(qb + (size_t)r*LL + l);
    bf16x8 kf = *(const bf16x8*)(kb + (size_t)r*LL + l);
    sqk = __builtin_amdgcn_mfma_f32_16x16x32_bf16(qf, kf, sqk, 0,0,0);
    sqq = __builtin_amdgcn_mfma_f32_16x16x32_bf16(qf, qf, sqq, 0,0,0);
    skk = __builtin_amdgcn_mfma_f32_16x16x32_bf16(kf, kf, skk, 0,0,0);
  }
  float* Sb = S + (size_t)((b*NH + h)*CH)*CH;
  #pragma unroll
  for (int i=0;i<4;++i)
    atomicAdd(&Sb[(kg*4+i)*CH + r], sqk[i]);    // row=c, col=d
  if ((r>>2) == kg){
    int i = r&3;                                 // diag lane: row==col==r
    atomicAdd(&nq[(b*NH+h)*CH + r], sqq[i]);
    atomicAdd(&nk[(b*NH+h)*CH + r], skk[i]);
  }
}

// ---------------------------------------------------------------------------
// K4: finalize attention and fold proj -> per-batch M2[o][j] (bf16, A-layout
// for k_out).
__global__ __launch_bounds__(256) void k_fin(const float* __restrict__ S,
                                             const float* __restrict__ nq,
                                             const float* __restrict__ nk,
                                             const float* __restrict__ temp,
                                             const float* __restrict__ attca,
                                             const float* __restrict__ proj,
                                             unsigned short* __restrict__ M2){
  int b = blockIdx.x;
  int t = threadIdx.x;
  __shared__ float attnf[NH][CH][CH];
  __shared__ float pl[DIMC*DIMC];
  for (int idx=t; idx<DIMC*DIMC; idx+=256) pl[idx] = proj[idx];
  if (t < 128){
    int h = t >> 4, c = t & 15;
    float tmpv = temp[h];
    float qn = fmaxf(sqrtf(nq[(b*NH+h)*CH + c]), 1e-12f);
    float row[CH], ex[CH], a1[CH];
    float m = -1e30f;
    #pragma unroll
    for (int d=0; d<CH; ++d){
      float kn = fmaxf(sqrtf(nk[(b*NH+h)*CH + d]), 1e-12f);
      float v = S[((b*NH+h)*CH + c)*CH + d] / (qn*kn) * tmpv;
      row[d] = v;
      m = fmaxf(m, v);
    }
    float sum = 0.f;
    #pragma unroll
    for (int d=0;d<CH;++d){ ex[d] = expf(row[d]-m); sum += ex[d]; }
    float inv = 1.f/sum;
    #pragma unroll
    for (int d=0;d<CH;++d){
      float rr = fmaxf(row[d], 0.f);
      float xx = rr*rr;
      float g = 0.5f * xx * (1.f + erff(xx * 0.70710678118654752440f));
      a1[d] = g * xx;
    }
    #pragma unroll
    for (int j=0;j<CH;++j){
      float sc=0.f, sh=0.f;
      #pragma unroll
      for (int i=0;i<CH;++i){
        sc = fmaf(attca[j*CH+i],      a1[i], sc);
        sh = fmaf(attca[(CH+j)*CH+i], a1[i], sh);
      }
      attnf[h][c][j] = ex[j]*inv*(1.f+sc) + sh;
    }
  }
  __syncthreads();
  // M2[o][j=(h,d)] = sum_c proj[o][h*16+c] * attnf[h][c][d]
  for (int idx=t; idx<DIMC*DIMC; idx+=256){
    int o = idx >> 7, j = idx & 127;
    int h = j >> 4, d = j & 15;
    float s = 0.f;
    #pragma unroll
    for (int c2=0;c2<CH;++c2) s = fmaf(pl[o*DIMC + h*CH + c2], attnf[h][c2][d], s);
    M2[(size_t)b*DIMC*DIMC + o*DIMC + j] = fbits(s);
  }
}

// ---------------------------------------------------------------------------
// K5: out[o][l] = sum_j M2[o][j] V[j][l] via MFMA.  V tile transposed inline
// into swizzled LDS [l][j]; A-frags from global M2 (L1-resident).
__global__ __launch_bounds__(256) void k_out(const unsigned short* __restrict__ qkvd,
                                             const unsigned short* __restrict__ M2,
                                             float* __restrict__ out){
  __shared__ u32x4 lds4[2048];              // 32 KB: [l=128][j=128] bf16 swizzled
  char* lds = (char*)lds4;
  int bid = blockIdx.x;
  int b = bid >> 9;
  int l0 = (bid & 511) << 7;
  int tid = threadIdx.x;
  const unsigned short* vb = qkvd + (size_t)(b*QKVC + 2*DIMC)*LL;

  // stage: task = (oct 0..15, lpair 0..63): read ushort2 along l from 8 rows,
  // emit two swizzled b128 writes.
  #pragma unroll
  for (int it=0; it<4; ++it){
    int task = it*256 + tid;
    int lp  = (task & 63) * 2;
    int oct = task >> 6;
    unsigned lo32[8];
    #pragma unroll
    for (int e=0;e<8;++e)
      lo32[e] = *(const unsigned int*)(vb + (size_t)(oct*8+e)*LL + l0 + lp); // 2 bf16
    u32x4 p0, p1;
    #pragma unroll
    for (int k=0;k<4;++k){
      unsigned a0 = lo32[2*k] & 0xffffu,  a1 = lo32[2*k] >> 16;
      unsigned b0 = lo32[2*k+1] & 0xffffu, b1 = lo32[2*k+1] >> 16;
      p0[k] = a0 | (b0<<16);   // l = lp
      p1[k] = a1 | (b1<<16);   // l = lp+1
    }
    *(u32x4*)(lds + lp*256     + ((oct ^ (lp&15))<<4))     = p0;
    *(u32x4*)(lds + (lp+1)*256 + ((oct ^ ((lp+1)&15))<<4)) = p1;
  }
  __syncthreads();

  int wid = tid >> 6, lane = tid & 63;
  int r = lane & 15, kg = lane >> 4;
  int ob = wid * 32;
  f32x4 acc[2][8];
  #pragma unroll
  for (int ft=0; ft<2; ++ft)
    #pragma unroll
    for (int nt=0; nt<8; ++nt) acc[ft][nt] = (f32x4)0.f;

  #pragma unroll
  for (int kb=0; kb<4; ++kb){
    bf16x8 a[2], bf[8];
    #pragma unroll
    for (int ft=0; ft<2; ++ft)
      a[ft] = *(const bf16x8*)(M2 + (size_t)b*DIMC*DIMC + (ob + ft*16 + r)*DIMC + kb*32 + kg*8);
    #pragma unroll
    for (int nt=0; nt<8; ++nt){
      int l = nt*16 + r;
      bf[nt] = *(const bf16x8*)(lds + l*256 + (((kb*4 + kg) ^ r)<<4));
    }
    #pragma unroll
    for (int ft=0; ft<2; ++ft)
      #pragma unroll
      for (int nt=0; nt<8; ++nt)
        acc[ft][nt] = __builtin_amdgcn_mfma_f32_16x16x32_bf16(a[ft], bf[nt], acc[ft][nt], 0,0,0);
  }

  float* ob_ptr = out + (size_t)b*DIMC*LL + l0;
  #pragma unroll
  for (int ft=0; ft<2; ++ft)
    #pragma unroll
    for (int nt=0; nt<8; ++nt)
      #pragma unroll
      for (int i=0;i<4;++i){
        int o = ob + ft*16 + kg*4 + i;
        ob_ptr[(size_t)o*LL + nt*16 + r] = acc[ft][nt][i];
      }
}

// ---------------------------------------------------------------------------
extern "C" void kernel_launch(void* const* d_in, const int* in_sizes, int n_in,
                              void* d_out, int out_size, void* d_ws, size_t ws_size,
                              hipStream_t stream){
  const float* x      = (const float*)d_in[0];
  const float* qkv_w  = (const float*)d_in[1];
  const float* dw_w   = (const float*)d_in[2];
  const float* proj_w = (const float*)d_in[3];
  const float* attca  = (const float*)d_in[4];
  const float* temp   = (const float*)d_in[5];
  float* out = (float*)d_out;

  char* ws = (char*)d_ws;
  size_t off = 0;
  unsigned short* qkv_pw = (unsigned short*)(ws + off); off += (size_t)BB*QKVC*LL*2;
  unsigned short* qkv_dw = (unsigned short*)(ws + off); off += (size_t)BB*QKVC*LL*2;
  float* S  = (float*)(ws + off); off += (size_t)BB*NH*CH*CH*4;
  float* nq = (float*)(ws + off); off += (size_t)BB*NH*CH*4;
  float* nk = (float*)(ws + off); off += (size_t)BB*NH*CH*4;
  unsigned short* wb = (unsigned short*)(ws + off); off += (size_t)QKVC*DIMC*2;
  unsigned short* M2 = (unsigned short*)(ws + off); off += (size_t)BB*DIMC*DIMC*2;

  hipMemsetAsync(S, 0, (size_t)(BB*NH*CH*CH + 2*BB*NH*CH)*4, stream);

  k_wb  <<<(QKVC*DIMC + 255)/256, 256, 0, stream>>>(qkv_w, wb);
  k_pw  <<<BB*512,      512, 0, stream>>>(x, wb, qkv_pw);
  k_dw  <<<BB*QKVC*32,  256, 0, stream>>>((const bf16*)qkv_pw, dw_w, (bf16*)qkv_dw);
  k_gram<<<BB*512,      256, 0, stream>>>(qkv_dw, S, nq, nk);
  k_fin <<<BB,          256, 0, stream>>>(S, nq, nk, temp, attca, proj_w, M2);
  k_out <<<BB*512,      256, 0, stream>>>(qkv_dw, M2, out);
}